// Round 5
// baseline (103.099 us; speedup 1.0000x reference)
//
#include <hip/hip_runtime.h>

// VolumetricRayMarcher: B=4, R=65536, S=128.
// R5: persistent waves + software-pipelined prefetch.
// Structure per wave-iteration = R4 (2 rays/wave, 32 lanes/ray, 4 samples/lane,
// fully-coalesced f32x4 loads, width-32 scan + butterfly). Each persistent wave
// grid-strides over ray-PAIRS, issuing the next iteration's 4 loads before
// computing the current one, so ~8 requests/wave stay in flight (counted vmcnt).

#define NSAMP 128
typedef float f32x4 __attribute__((ext_vector_type(4)));

__global__ __launch_bounds__(256) void VolumetricRayMarcher_kernel(
    const float* __restrict__ rgb,      // [n_rays, 128, 3]
    const float* __restrict__ density,  // [n_rays, 128]
    float* __restrict__ out,            // [n_rays, 3]
    int n_pairs) {                      // n_rays / 2
    const int lane = threadIdx.x & 63;
    const int h    = lane >> 5;          // which ray of the pair
    const int l    = lane & 31;          // lane within 32-lane half
    const int wid  = (int)((blockIdx.x * blockDim.x + threadIdx.x) >> 6);
    const int nw   = (int)((gridDim.x * blockDim.x) >> 6);

    const float DELTA = 1.9f / 127.0f;
    const float dl3 = (l == 31) ? 1e10f : DELTA;   // sample 127 delta

    int pair = wid;
    if (pair >= n_pairs) return;

    // ---- prologue: load iteration 0 ----
    int ray = pair * 2 + h;
    f32x4 d4 = ((const f32x4*)(density + (size_t)ray * NSAMP))[l];
    const f32x4* rg = (const f32x4*)(rgb + (size_t)ray * (NSAMP * 3)) + (size_t)l * 3;
    f32x4 a = rg[0];   // s0.r s0.g s0.b s1.r
    f32x4 b = rg[1];   // s1.g s1.b s2.r s2.g
    f32x4 c = rg[2];   // s2.b s3.r s3.g s3.b

    while (true) {
        // ---- prefetch next iteration (wave-uniform condition) ----
        const int npair = pair + nw;
        const bool have_next = (npair < n_pairs);
        f32x4 nd4 = d4, na = a, nb = b, nc = c;
        if (have_next) {
            const int nray = npair * 2 + h;
            nd4 = ((const f32x4*)(density + (size_t)nray * NSAMP))[l];
            const f32x4* nrg = (const f32x4*)(rgb + (size_t)nray * (NSAMP * 3)) + (size_t)l * 3;
            na = nrg[0];
            nb = nrg[1];
            nc = nrg[2];
        }

        // ---- alphas / factors for samples 4l..4l+3 ----
        const float al0 = 1.0f - __expf(-d4.x * DELTA);
        const float al1 = 1.0f - __expf(-d4.y * DELTA);
        const float al2 = 1.0f - __expf(-d4.z * DELTA);
        const float al3 = 1.0f - __expf(-d4.w * dl3);
        const float f0 = 1.0f - al0 + 1e-10f;
        const float f1 = 1.0f - al1 + 1e-10f;
        const float f2 = 1.0f - al2 + 1e-10f;
        const float f3 = 1.0f - al3 + 1e-10f;

        // ---- exclusive cumprod: width-32 scan of per-lane products ----
        float p = (f0 * f1) * (f2 * f3);
        #pragma unroll
        for (int off = 1; off < 32; off <<= 1) {
            float o = __shfl_up(p, off, 32);
            if (l >= off) p *= o;
        }
        float excl = __shfl_up(p, 1, 32);
        if (l == 0) excl = 1.0f;

        float t = excl;
        const float w0 = al0 * t; t *= f0;
        const float w1 = al1 * t; t *= f1;
        const float w2 = al2 * t; t *= f2;
        const float w3 = al3 * t;

        // ---- weighted rgb, static channel mapping ----
        float acc0 = w0 * a.x + w1 * a.w + w2 * b.z + w3 * c.y;
        float acc1 = w0 * a.y + w1 * b.x + w2 * b.w + w3 * c.z;
        float acc2 = w0 * a.z + w1 * b.y + w2 * c.x + w3 * c.w;

        // ---- width-32 butterfly reduce (both rays in parallel) ----
        #pragma unroll
        for (int off = 16; off > 0; off >>= 1) {
            acc0 += __shfl_xor(acc0, off, 32);
            acc1 += __shfl_xor(acc1, off, 32);
            acc2 += __shfl_xor(acc2, off, 32);
        }

        if (l == 0) {
            float* o = out + (size_t)(pair * 2 + h) * 3;
            o[0] = acc0;
            o[1] = acc1;
            o[2] = acc2;
        }

        if (!have_next) break;
        pair = npair;
        d4 = nd4; a = na; b = nb; c = nc;
    }
}

extern "C" void kernel_launch(void* const* d_in, const int* in_sizes, int n_in,
                              void* d_out, int out_size, void* d_ws, size_t ws_size,
                              hipStream_t stream) {
    const float* rgb     = (const float*)d_in[0];   // [B,R,S,3] f32
    const float* density = (const float*)d_in[1];   // [B,R,S]   f32
    float* out = (float*)d_out;                     // [B,R,3]   f32

    const int n_rays  = in_sizes[1] / NSAMP;        // B*R = 262144
    const int n_pairs = n_rays / 2;                 // 131072 (n_rays is even)

    // Persistent grid: 2048 blocks x 256 threads = 8192 waves (32 waves/CU),
    // 16 pair-iterations per wave.
    int blocks = (n_pairs + 3) / 4;
    if (blocks > 2048) blocks = 2048;

    hipLaunchKernelGGL(VolumetricRayMarcher_kernel, dim3(blocks), dim3(256), 0, stream,
                       rgb, density, out, n_pairs);
}

// Round 6
// 94.755 us; speedup vs baseline: 1.0881x; 1.0881x over previous
//
#include <hip/hip_runtime.h>

// VolumetricRayMarcher: B=4, R=65536, S=128.
// One 64-lane wave per ray, 2 samples per lane.  (Best variant: R1, 94.8 µs.)
// out[ray] = sum_s alpha_s * T_s * rgb_s, T_s = prod_{j<s} (1 - alpha_j + 1e-10)
// alpha_s = 1 - exp(-density_s * delta_s), delta_s = 1.9/127 (s<127), 1e10 (s=127).
//
// Measured at the memory roofline: 540 MB min traffic -> 5.7 TB/s effective
// (~90% of the 6.29 TB/s D2D copy ceiling). A/B'd against fully-coalesced rgb
// (R3/R4), LDS weight redistribution (R2/R3), and persistent-wave prefetch
// (R5): all null or negative at identical FETCH_SIZE.

#define NSAMP 128
#define NEAR_T 0.1f
#define FAR_T 2.0f

__global__ __launch_bounds__(256) void VolumetricRayMarcher_kernel(
    const float* __restrict__ rgb,      // [n_rays, 128, 3]
    const float* __restrict__ density,  // [n_rays, 128]
    float* __restrict__ out,            // [n_rays, 3]
    int n_rays) {
    const int lane = threadIdx.x & 63;
    const int wave = threadIdx.x >> 6;
    const int ray  = blockIdx.x * 4 + wave;
    if (ray >= n_rays) return;

    const float DELTA = (FAR_T - NEAR_T) / (float)(NSAMP - 1);  // 1.9/127

    // ---- density: 2 samples per lane, coalesced float2 (512 B / wave) ----
    const float2 dpair = ((const float2*)(density + (size_t)ray * NSAMP))[lane];

    const float delta1 = (lane == 63) ? 1e10f : DELTA;

    const float alpha0 = 1.0f - __expf(-dpair.x * DELTA);
    const float alpha1 = 1.0f - __expf(-dpair.y * delta1);
    const float f0 = 1.0f - alpha0 + 1e-10f;
    const float f1 = 1.0f - alpha1 + 1e-10f;

    // ---- exclusive cumprod across 128 samples: wave scan of per-lane products ----
    float p = f0 * f1;
    #pragma unroll
    for (int off = 1; off < 64; off <<= 1) {
        float other = __shfl_up(p, off, 64);
        if (lane >= off) p *= other;
    }
    float excl = __shfl_up(p, 1, 64);   // product of all samples before this lane's s0
    if (lane == 0) excl = 1.0f;

    const float w0 = alpha0 * excl;
    const float w1 = alpha1 * excl * f0;

    // ---- rgb: 6 floats per lane = 2 samples, 3x float2 (1536 B / wave) ----
    const float2* rgb2 = (const float2*)(rgb + (size_t)ray * NSAMP * 3);
    const float2 a = rgb2[lane * 3 + 0];
    const float2 b = rgb2[lane * 3 + 1];
    const float2 c = rgb2[lane * 3 + 2];
    // sample s0 rgb = (a.x, a.y, b.x); sample s1 rgb = (b.y, c.x, c.y)
    float cr = w0 * a.x + w1 * b.y;
    float cg = w0 * a.y + w1 * c.x;
    float cb = w0 * b.x + w1 * c.y;

    // ---- wave reduce (butterfly) ----
    #pragma unroll
    for (int off = 32; off > 0; off >>= 1) {
        cr += __shfl_xor(cr, off, 64);
        cg += __shfl_xor(cg, off, 64);
        cb += __shfl_xor(cb, off, 64);
    }

    if (lane == 0) {
        float* o = out + (size_t)ray * 3;
        o[0] = cr;
        o[1] = cg;
        o[2] = cb;
    }
}

extern "C" void kernel_launch(void* const* d_in, const int* in_sizes, int n_in,
                              void* d_out, int out_size, void* d_ws, size_t ws_size,
                              hipStream_t stream) {
    const float* rgb     = (const float*)d_in[0];   // [B,R,S,3] f32
    const float* density = (const float*)d_in[1];   // [B,R,S]   f32
    float* out = (float*)d_out;                     // [B,R,3]   f32

    const int n_rays = in_sizes[1] / NSAMP;         // B*R = 262144
    const int blocks = (n_rays + 3) / 4;            // 4 waves (rays) per 256-thread block

    hipLaunchKernelGGL(VolumetricRayMarcher_kernel, dim3(blocks), dim3(256), 0, stream,
                       rgb, density, out, n_rays);
}